// Round 7
// baseline (312.200 us; speedup 1.0000x reference)
//
#include <hip/hip_runtime.h>

typedef __bf16 bf16_t;
typedef __bf16 bf16x8 __attribute__((ext_vector_type(8)));
typedef __bf16 bf16x2 __attribute__((ext_vector_type(2)));
typedef float  f32x4  __attribute__((ext_vector_type(4)));

#define MFMA16(a,b,c) __builtin_amdgcn_mfma_f32_16x16x32_bf16((a),(b),(c),0,0,0)

// ---- constants (problem is fixed-shape) ----
#define BB 8
#define NN 2048
#define CC 128
#define CIN 64
#define KNB 16            // neighbors
#define BNT (BB*NN)       // 16384 points

// XCD affinity: consecutive blockIdx round-robin over 8 XCDs; remap so the
// batch a block works on == blockIdx%8 == its XCD (R6: cut attn FETCH 38->13.5MB).
static __device__ __forceinline__ int remap256(int x) { return ((x & 7) << 5) | (x >> 3); }

static __device__ __forceinline__ bf16x8 cvt8(const float* src) {
  f32x4 a0 = *(const f32x4*)src;
  f32x4 a1 = *(const f32x4*)(src + 4);
  bf16x8 fr;
  fr[0] = (__bf16)a0[0]; fr[1] = (__bf16)a0[1]; fr[2] = (__bf16)a0[2]; fr[3] = (__bf16)a0[3];
  fr[4] = (__bf16)a1[0]; fr[5] = (__bf16)a1[1]; fr[6] = (__bf16)a1[2]; fr[7] = (__bf16)a1[3];
  return fr;
}

// ============================================================
// Kernel 0: composite weights (fp32 VALU, exact):
//   Waq = Wa@Wq, Wak = Wa@Wk, Wda = Wa@Wd2, cb = ba + Wa@bd2
// grid (8,3): x = 16-row group, y = which matrix. block 256.
// ============================================================
__global__ __launch_bounds__(256) void compw_k(
    const float* __restrict__ Wa, const float* __restrict__ Wq,
    const float* __restrict__ Wk, const float* __restrict__ Wd2,
    const float* __restrict__ ba, const float* __restrict__ bd2,
    float* __restrict__ Waq, float* __restrict__ Wak, float* __restrict__ Wda,
    float* __restrict__ cb) {
  __shared__ float Bs[64 * 128];     // 32 KB, staged in two halves
  int t = threadIdx.x;
  int mat = blockIdx.y;
  const float* B = mat == 0 ? Wq : mat == 1 ? Wk : Wd2;
  float* O = mat == 0 ? Waq : mat == 1 ? Wak : Wda;
  int row = blockIdx.x * 16 + (t >> 4);
  int c0 = (t & 15) * 8;
  const float* ar = Wa + row * 128;
  float acc[8] = {};
  for (int half = 0; half < 2; ++half) {
    __syncthreads();
    for (int i = t; i < 64 * 128 / 4; i += 256)
      ((f32x4*)Bs)[i] = ((const f32x4*)(B + half * 64 * 128))[i];
    __syncthreads();
    #pragma unroll 4
    for (int e = 0; e < 64; ++e) {
      float av = ar[half * 64 + e];
      #pragma unroll
      for (int j = 0; j < 8; ++j) acc[j] = fmaf(av, Bs[e * 128 + c0 + j], acc[j]);
    }
  }
  #pragma unroll
  for (int j = 0; j < 8; ++j) O[row * 128 + c0 + j] = acc[j];
  if (mat == 2 && blockIdx.x == 0 && t < 128) {
    float s = 0.f;
    for (int e = 0; e < 128; ++e) s = fmaf(Wa[t * 128 + e], bd2[e], s);
    cb[t] = ba[t] + s;
  }
}

// ============================================================
// Kernel 1: in_proj + LN1, MFMA-based (unchanged from R6).
// ============================================================
__global__ __launch_bounds__(256) void inproj_ln_k(
    const float* __restrict__ x, const float* __restrict__ Win, const float* __restrict__ bin,
    const float* __restrict__ g1, const float* __restrict__ b1,
    float* __restrict__ h, bf16_t* __restrict__ hnb) {
  __shared__ bf16_t As[64 * 72];
  __shared__ bf16_t Bs[128 * 72];
  __shared__ float hs[64 * 132];
  int t = threadIdx.x;
  int lane = t & 63, w = t >> 6, quad = lane >> 4, l15 = lane & 15;
  int mBase = remap256(blockIdx.x) * 64;
  int b = mBase >> 11, n0 = mBase & (NN - 1);
  const float* xb = x + (size_t)b * CIN * NN;
  {
    int k = t >> 2, part = t & 3;
    #pragma unroll
    for (int i = 0; i < 4; ++i) {
      f32x4 v = *(const f32x4*)(xb + (size_t)k * NN + n0 + part * 16 + i * 4);
      #pragma unroll
      for (int j2 = 0; j2 < 4; ++j2) As[(part * 16 + i * 4 + j2) * 72 + k] = (__bf16)v[j2];
    }
  }
  {
    int row = t >> 1, seg = (t & 1) * 32;
    #pragma unroll
    for (int i = 0; i < 4; ++i)
      *(bf16x8*)(&Bs[row * 72 + seg + i * 8]) = cvt8(Win + (size_t)row * CIN + seg + i * 8);
  }
  __syncthreads();
  f32x4 acc[2][4] = {};
  #pragma unroll
  for (int s = 0; s < 2; ++s) {
    bf16x8 af[4];
    #pragma unroll
    for (int mt = 0; mt < 4; ++mt)
      af[mt] = *(const bf16x8*)(&As[(mt * 16 + l15) * 72 + s * 32 + quad * 8]);
    #pragma unroll
    for (int t2 = 0; t2 < 2; ++t2) {
      bf16x8 bfr = *(const bf16x8*)(&Bs[((w * 2 + t2) * 16 + l15) * 72 + s * 32 + quad * 8]);
      #pragma unroll
      for (int mt = 0; mt < 4; ++mt) acc[t2][mt] = MFMA16(af[mt], bfr, acc[t2][mt]);
    }
  }
  #pragma unroll
  for (int t2 = 0; t2 < 2; ++t2) {
    int col = (w * 2 + t2) * 16 + l15;
    float bv = bin[col];
    #pragma unroll
    for (int mt = 0; mt < 4; ++mt)
      #pragma unroll
      for (int reg = 0; reg < 4; ++reg)
        hs[(mt * 16 + quad * 4 + reg) * 132 + col] = acc[t2][mt][reg] + bv;
  }
  __syncthreads();
  {
    int row = t >> 2, c0 = (t & 3) * 32;
    float v[32];
    #pragma unroll
    for (int i = 0; i < 8; ++i) *(f32x4*)(v + i * 4) = *(const f32x4*)(&hs[row * 132 + c0 + i * 4]);
    float s1 = 0.f, s2 = 0.f;
    #pragma unroll
    for (int i = 0; i < 32; ++i) { s1 += v[i]; s2 += v[i] * v[i]; }
    s1 += __shfl_xor(s1, 1); s1 += __shfl_xor(s1, 2);
    s2 += __shfl_xor(s2, 1); s2 += __shfl_xor(s2, 2);
    float mu = s1 * (1.f / CC);
    float var = s2 * (1.f / CC) - mu * mu;
    float rs = rsqrtf(var + 1e-5f);
    float* hrow = h + (size_t)(mBase + row) * CC + c0;
    #pragma unroll
    for (int i = 0; i < 8; ++i) *(f32x4*)(hrow + i * 4) = *(const f32x4*)(v + i * 4);
    bf16_t* hnrow = hnb + (size_t)(mBase + row) * CC + c0;
    #pragma unroll
    for (int i = 0; i < 4; ++i) {
      f32x4 g4a = ((const f32x4*)g1)[(c0 >> 2) + i * 2],     g4b = ((const f32x4*)g1)[(c0 >> 2) + i * 2 + 1];
      f32x4 b4a = ((const f32x4*)b1)[(c0 >> 2) + i * 2],     b4b = ((const f32x4*)b1)[(c0 >> 2) + i * 2 + 1];
      bf16x8 o;
      #pragma unroll
      for (int j = 0; j < 4; ++j) o[j]     = (__bf16)((v[i * 8 + j]     - mu) * rs * g4a[j] + b4a[j]);
      #pragma unroll
      for (int j = 0; j < 4; ++j) o[4 + j] = (__bf16)((v[i * 8 + 4 + j] - mu) * rs * g4b[j] + b4b[j]);
      *(bf16x8*)(hnrow + i * 8) = o;
    }
  }
}

// ============================================================
// Kernel 3: KNN (unchanged from R6: packed (dist,idx) doubles, bitonic
// top-8 per lane, butterfly extraction).
// ============================================================
static __device__ __forceinline__ void cas(double& a, double& b) {
  double lo = fmin(a, b), hi = fmax(a, b); a = lo; b = hi;
}
#define S8(K,o) \
  cas(K[o+0],K[o+1]); cas(K[o+2],K[o+3]); cas(K[o+4],K[o+5]); cas(K[o+6],K[o+7]); \
  cas(K[o+0],K[o+2]); cas(K[o+1],K[o+3]); cas(K[o+4],K[o+6]); cas(K[o+5],K[o+7]); \
  cas(K[o+1],K[o+2]); cas(K[o+5],K[o+6]); \
  cas(K[o+0],K[o+4]); cas(K[o+1],K[o+5]); cas(K[o+2],K[o+6]); cas(K[o+3],K[o+7]); \
  cas(K[o+2],K[o+4]); cas(K[o+3],K[o+5]); \
  cas(K[o+1],K[o+2]); cas(K[o+3],K[o+4]); cas(K[o+5],K[o+6]);
#define M8(K,a,b) \
  K[a+0]=fmin(K[a+0],K[b+7]); K[a+1]=fmin(K[a+1],K[b+6]); K[a+2]=fmin(K[a+2],K[b+5]); K[a+3]=fmin(K[a+3],K[b+4]); \
  K[a+4]=fmin(K[a+4],K[b+3]); K[a+5]=fmin(K[a+5],K[b+2]); K[a+6]=fmin(K[a+6],K[b+1]); K[a+7]=fmin(K[a+7],K[b+0]); \
  cas(K[a+0],K[a+4]); cas(K[a+1],K[a+5]); cas(K[a+2],K[a+6]); cas(K[a+3],K[a+7]); \
  cas(K[a+0],K[a+2]); cas(K[a+1],K[a+3]); cas(K[a+4],K[a+6]); cas(K[a+5],K[a+7]); \
  cas(K[a+0],K[a+1]); cas(K[a+2],K[a+3]); cas(K[a+4],K[a+5]); cas(K[a+6],K[a+7]);

__global__ __launch_bounds__(256) void knn_k(const float* __restrict__ p, int* __restrict__ idxo) {
  __shared__ float px[NN], py[NN], pz[NN];
  int t = threadIdx.x;
  int b = blockIdx.x >> 9;
  int g = blockIdx.x & 511;
  const float* pb = p + (size_t)b * 3 * NN;
  for (int i = t; i < NN; i += 256) { px[i] = pb[i]; py[i] = pb[NN + i]; pz[i] = pb[2 * NN + i]; }
  __syncthreads();
  int w = t >> 6, lane = t & 63;
  int n = g * 4 + w;
  float pnx = px[n], pny = py[n], pnz = pz[n];
  double key[32];
  #pragma unroll
  for (int s = 0; s < 32; ++s) {
    int m = s * 64 + lane;
    float dx = pnx - px[m], dy = pny - py[m], dz = pnz - pz[m];
    float dist = dx * dx + dy * dy + dz * dz;
    unsigned db = (m == n) ? 0x7F800000u : __float_as_uint(dist);
    key[s] = __hiloint2double((int)db, m);
  }
  S8(key, 0); S8(key, 8); S8(key, 16); S8(key, 24);
  M8(key, 0, 8); M8(key, 16, 24); M8(key, 0, 16);
  const double DINF = __hiloint2double(0x7F900000, 0);
  int* myout = idxo + ((size_t)b * NN + n) * KNB;
  #pragma unroll 1
  for (int r = 0; r < 16; ++r) {
    double gm = key[0];
    #pragma unroll
    for (int off = 1; off < 64; off <<= 1) {
      double o = __shfl_xor(gm, off);
      gm = fmin(gm, o);
    }
    if (lane == 0) myout[r] = __double2loint(gm);
    bool win = (key[0] == gm);
    key[0] = win ? key[1] : key[0];
    key[1] = win ? key[2] : key[1];
    key[2] = win ? key[3] : key[2];
    key[3] = win ? key[4] : key[3];
    key[4] = win ? key[5] : key[4];
    key[5] = win ? key[6] : key[5];
    key[6] = win ? key[7] : key[6];
    key[7] = win ? DINF   : key[7];
  }
}

// ============================================================
// GEMM body + kernels (unchanged from R6).
// ============================================================
template<int EPI>
static __device__ __forceinline__ void gemm_body(
    const bf16_t* __restrict__ Ab,
    const float* __restrict__ W, const float* __restrict__ bias,
    float* __restrict__ outF, bf16_t* __restrict__ outB,
    const float* __restrict__ resid,
    int mBase, int nBase, int Ncol, int Kdim) {
  __shared__ bf16_t As[64 * 40];
  __shared__ bf16_t Bs[64 * 40];
  int t = threadIdx.x;
  int lane = t & 63, w = t >> 6, quad = lane >> 4, l15 = lane & 15;
  int r = t >> 2, seg = (t & 3) * 8;
  f32x4 acc[4] = {{0,0,0,0},{0,0,0,0},{0,0,0,0},{0,0,0,0}};
  for (int k0 = 0; k0 < Kdim; k0 += 32) {
    __syncthreads();
    *(bf16x8*)(&As[r * 40 + seg]) = *(const bf16x8*)(Ab + (size_t)(mBase + r) * Kdim + k0 + seg);
    *(bf16x8*)(&Bs[r * 40 + seg]) = cvt8(W + (size_t)(nBase + r) * Kdim + k0 + seg);
    __syncthreads();
    bf16x8 bfr = *(const bf16x8*)(&Bs[(w * 16 + l15) * 40 + quad * 8]);
    #pragma unroll
    for (int mt = 0; mt < 4; ++mt) {
      bf16x8 afr = *(const bf16x8*)(&As[(mt * 16 + l15) * 40 + quad * 8]);
      acc[mt] = MFMA16(afr, bfr, acc[mt]);
    }
  }
  int n = nBase + w * 16 + l15;
  float bv = bias ? bias[n] : 0.f;
  #pragma unroll
  for (int mt = 0; mt < 4; ++mt) {
    #pragma unroll
    for (int reg = 0; reg < 4; ++reg) {
      int m = mBase + mt * 16 + quad * 4 + reg;
      float val = acc[mt][reg] + bv;
      if (EPI == 0) {
        outF[(size_t)m * Ncol + n] = val;
      } else if (EPI == 1) {
        outB[(size_t)m * Ncol + n] = (__bf16)fmaxf(val, 0.f);
      } else if (EPI == 3) {
        outB[(size_t)m * Ncol + n] = (__bf16)val;
      } else {
        val += resid[(size_t)m * CC + n];
        int bo = m >> 11, np = m & (NN - 1);
        outF[((size_t)bo * CC + n) * NN + np] = val;
      }
    }
  }
}

template<int EPI>
__global__ __launch_bounds__(256) void gemm_k(
    const bf16_t* __restrict__ Ab,
    const float* __restrict__ W, const float* __restrict__ bias,
    float* __restrict__ outF, bf16_t* __restrict__ outB,
    const float* __restrict__ resid,
    int Ncol, int Kdim) {
  gemm_body<EPI>(Ab, W, bias, outF, outB, resid, remap256(blockIdx.x) * 64, blockIdx.y * 64, Ncol, Kdim);
}

// fused qa/ka/v: now emits qa = hn@Waq^T (fp32), ka = hn@Wak^T (bf16), v (bf16)
__global__ __launch_bounds__(256) void gemm_qkv_k(
    const bf16_t* __restrict__ hnb,
    const float* __restrict__ Waq, const float* __restrict__ Wak, const float* __restrict__ Wv,
    float* __restrict__ qa, bf16_t* __restrict__ ka, bf16_t* __restrict__ vb) {
  int sel = blockIdx.y >> 1;
  int nB = (blockIdx.y & 1) * 64, mB = remap256(blockIdx.x) * 64;
  if (sel == 0)      gemm_body<0>(hnb, Waq, nullptr, qa, nullptr, nullptr, mB, nB, CC, CC);
  else if (sel == 1) gemm_body<3>(hnb, Wak, nullptr, nullptr, ka, nullptr, mB, nB, CC, CC);
  else               gemm_body<3>(hnb, Wv, nullptr, nullptr, vb, nullptr, mB, nB, CC, CC);
}

// ============================================================
// Kernel 5: fused neighbor attention v4 — u-matrix ELIMINATED via
// composite weights:
//   logits = qa - ka_j + t@Wda^T + cb   (qa=q@Wa^T, ka=k@Wa^T precomputed)
// t-fragments in A-layout registers; TWO MFMA chains (d = t@Wd2^T and
// la = t@Wda^T) back-to-back, no LDS round-trip, 2 barriers total.
// LDS ~5.3 KB. grid = BNT/4, block = 256, batch = blockIdx&7 (XCD-local).
// ============================================================
__global__ __launch_bounds__(256, 3) void attn_k(
    const float* __restrict__ qabuf, const bf16_t* __restrict__ kabuf, const bf16_t* __restrict__ vbuf,
    const float* __restrict__ p, const int* __restrict__ idx,
    const float* __restrict__ Wd1, const float* __restrict__ bd1,
    const float* __restrict__ Wd2, const float* __restrict__ Wda,
    const float* __restrict__ cb, const float* __restrict__ bd2,
    const float* __restrict__ g2, const float* __restrict__ b2,
    const float* __restrict__ h, float* __restrict__ hres, bf16_t* __restrict__ h2) {
  __shared__ f32x4 wd1s[128];          // {Wd1[c][0..2], bd1[c]}
  __shared__ f32x4 rels4[64];          // {rx,ry,rz,0}
  __shared__ int idxs[64];
  __shared__ float hrs[4 * 128];
  int t = threadIdx.x;
  int lane = t & 63, w = t >> 6, quad = lane >> 4, l15 = lane & 15;
  int batch = blockIdx.x & 7, grp = blockIdx.x >> 3;
  int bn0 = batch * NN + grp * 4;
  const float* pb = p + (size_t)batch * 3 * NN;
  int col0 = w * 32 + l15;
  int col1 = col0 + 16;

  // persistent B fragments: Bd (Wd2) and Bl (Wda); wave w owns c-tiles 2w,2w+1
  bf16x8 Bd[2][4], Bl[2][4];
  #pragma unroll
  for (int t2 = 0; t2 < 2; ++t2) {
    int row = w * 32 + t2 * 16 + l15;
    #pragma unroll
    for (int s = 0; s < 4; ++s) {
      Bd[t2][s] = cvt8(Wd2 + (size_t)row * CC + s * 32 + quad * 8);
      Bl[t2][s] = cvt8(Wda + (size_t)row * CC + s * 32 + quad * 8);
    }
  }

  // phase 0: idx, rel, wd1 staging
  if (t < 64) {
    int jj = idx[(size_t)bn0 * KNB + t];
    idxs[t] = jj;
    int npt = grp * 4 + (t >> 4);
    f32x4 rv;
    rv[0] = pb[npt]          - pb[jj];
    rv[1] = pb[NN + npt]     - pb[NN + jj];
    rv[2] = pb[2 * NN + npt] - pb[2 * NN + jj];
    rv[3] = 0.f;
    rels4[t] = rv;
  }
  if (t < 128) {
    f32x4 wv;
    wv[0] = Wd1[t * 3]; wv[1] = Wd1[t * 3 + 1]; wv[2] = Wd1[t * 3 + 2]; wv[3] = bd1[t];
    wd1s[t] = wv;
  }
  __syncthreads();

  // t-fragments in registers (A-layout) feeding BOTH MFMA chains
  f32x4 relv[4];
  #pragma unroll
  for (int mt = 0; mt < 4; ++mt) relv[mt] = rels4[mt * 16 + l15];
  f32x4 accd[2][4] = {};   // d   = t @ Wd2^T
  f32x4 accl[2][4] = {};   // la  = t @ Wda^T
  #pragma unroll
  for (int s = 0; s < 4; ++s) {
    bf16x8 af[4];
    #pragma unroll
    for (int j = 0; j < 8; ++j) {
      f32x4 wv = wd1s[s * 32 + quad * 8 + j];
      #pragma unroll
      for (int mt = 0; mt < 4; ++mt) {
        float tv = fmaf(wv[0], relv[mt][0], fmaf(wv[1], relv[mt][1], fmaf(wv[2], relv[mt][2], wv[3])));
        af[mt][j] = (__bf16)fmaxf(tv, 0.f);
      }
    }
    #pragma unroll
    for (int t2 = 0; t2 < 2; ++t2)
      #pragma unroll
      for (int mt = 0; mt < 4; ++mt) {
        accd[t2][mt] = MFMA16(af[mt], Bd[t2][s], accd[t2][mt]);
        accl[t2][mt] = MFMA16(af[mt], Bl[t2][s], accl[t2][mt]);
      }
  }

  // direct gathers at C/D-layout positions (Bd/Bl/af now dead)
  float qv[2][4];
  #pragma unroll
  for (int mt = 0; mt < 4; ++mt) {
    qv[0][mt] = qabuf[(size_t)(bn0 + mt) * CC + col0];
    qv[1][mt] = qabuf[(size_t)(bn0 + mt) * CC + col1];
  }
  float kav[2][4][4], vv[2][4][4];
  #pragma unroll
  for (int mt = 0; mt < 4; ++mt)
    #pragma unroll
    for (int reg = 0; reg < 4; ++reg) {
      size_t base = (size_t)(batch * NN + idxs[mt * 16 + quad * 4 + reg]) * CC;
      kav[0][mt][reg] = (float)kabuf[base + col0];
      kav[1][mt][reg] = (float)kabuf[base + col1];
      vv[0][mt][reg]  = (float)vbuf[base + col0];
      vv[1][mt][reg]  = (float)vbuf[base + col1];
    }
  float hv[2][4];
  if (quad == 0) {
    #pragma unroll
    for (int mt = 0; mt < 4; ++mt) {
      hv[0][mt] = h[(size_t)(bn0 + mt) * CC + col0];
      hv[1][mt] = h[(size_t)(bn0 + mt) * CC + col1];
    }
  }

  // logits = qa - ka + la + cb ; softmax over j ; y = sum a*(v+d)
  #pragma unroll
  for (int t2 = 0; t2 < 2; ++t2) {
    int col = t2 ? col1 : col0;
    float cbv = cb[col];
    float b2v = bd2[col];
    #pragma unroll
    for (int mt = 0; mt < 4; ++mt) {
      float qc = qv[t2][mt] + cbv;
      float lv0 = qc - kav[t2][mt][0] + accl[t2][mt][0];
      float lv1 = qc - kav[t2][mt][1] + accl[t2][mt][1];
      float lv2 = qc - kav[t2][mt][2] + accl[t2][mt][2];
      float lv3 = qc - kav[t2][mt][3] + accl[t2][mt][3];
      float mx = fmaxf(fmaxf(lv0, lv1), fmaxf(lv2, lv3));
      mx = fmaxf(mx, __shfl_xor(mx, 16));
      mx = fmaxf(mx, __shfl_xor(mx, 32));
      float e0 = __expf(lv0 - mx), e1 = __expf(lv1 - mx);
      float e2 = __expf(lv2 - mx), e3 = __expf(lv3 - mx);
      float ss = e0 + e1 + e2 + e3;
      ss += __shfl_xor(ss, 16); ss += __shfl_xor(ss, 32);
      float yv = e0 * (vv[t2][mt][0] + accd[t2][mt][0] + b2v)
               + e1 * (vv[t2][mt][1] + accd[t2][mt][1] + b2v)
               + e2 * (vv[t2][mt][2] + accd[t2][mt][2] + b2v)
               + e3 * (vv[t2][mt][3] + accd[t2][mt][3] + b2v);
      yv += __shfl_xor(yv, 16); yv += __shfl_xor(yv, 32);
      if (quad == 0) {
        float hvv = hv[t2][mt] + yv / ss;
        hres[(size_t)(bn0 + mt) * CC + col] = hvv;
        hrs[mt * 128 + col] = hvv;
      }
    }
  }
  __syncthreads();

  // fused LN2: wave w normalizes point w, writes h2 bf16
  {
    int c0 = lane * 2;
    float v0 = hrs[w * 128 + c0], v1 = hrs[w * 128 + c0 + 1];
    float s1 = v0 + v1, s2 = v0 * v0 + v1 * v1;
    #pragma unroll
    for (int off = 1; off < 64; off <<= 1) { s1 += __shfl_xor(s1, off); s2 += __shfl_xor(s2, off); }
    float mu = s1 * (1.f / CC);
    float var = s2 * (1.f / CC) - mu * mu;
    float rs = rsqrtf(var + 1e-5f);
    bf16x2 o;
    o[0] = (__bf16)((v0 - mu) * rs * g2[c0] + b2[c0]);
    o[1] = (__bf16)((v1 - mu) * rs * g2[c0 + 1] + b2[c0 + 1]);
    *(bf16x2*)(h2 + (size_t)(bn0 + w) * CC + c0) = o;
  }
}

// ============================================================
extern "C" void kernel_launch(void* const* d_in, const int* in_sizes, int n_in,
                              void* d_out, int out_size, void* d_ws, size_t ws_size,
                              hipStream_t stream) {
  const float* x   = (const float*)d_in[0];
  const float* p   = (const float*)d_in[1];
  const float* Win = (const float*)d_in[2];
  const float* bin = (const float*)d_in[3];
  const float* Wq  = (const float*)d_in[4];
  const float* Wk  = (const float*)d_in[5];
  const float* Wv  = (const float*)d_in[6];
  const float* Wd1 = (const float*)d_in[7];
  const float* bd1 = (const float*)d_in[8];
  const float* Wd2 = (const float*)d_in[9];
  const float* bd2 = (const float*)d_in[10];
  const float* Wa  = (const float*)d_in[11];
  const float* ba  = (const float*)d_in[12];
  const float* g1  = (const float*)d_in[13];
  const float* b1  = (const float*)d_in[14];
  const float* g2  = (const float*)d_in[15];
  const float* b2  = (const float*)d_in[16];
  const float* Wf1 = (const float*)d_in[17];
  const float* bf1 = (const float*)d_in[18];
  const float* Wf2 = (const float*)d_in[19];
  const float* bf2 = (const float*)d_in[20];
  float* out = (float*)d_out;

  const size_t SZ = (size_t)BNT * CC;   // 2,097,152
  float* wsf = (float*)d_ws;
  float*  h    = wsf;
  bf16_t* hnb  = (bf16_t*)(wsf + SZ);
  float*  hres = wsf + SZ;
  float*  qa   = wsf + 2 * SZ;
  bf16_t* kab  = (bf16_t*)(wsf + 3 * SZ);
  bf16_t* vb   = kab + SZ;
  bf16_t* g    = (bf16_t*)(wsf + 2 * SZ);
  bf16_t* h2   = (bf16_t*)(wsf + 4 * SZ);
  int*    idxw = (int*)(wsf + 4 * SZ + SZ / 2);
  float*  Waq  = wsf + 4 * SZ + SZ / 2 + (size_t)BNT * KNB;  // after idx (1MB)
  float*  Wak  = Waq + 16384;
  float*  Wda  = Wak + 16384;
  float*  cbv  = Wda + 16384;

  compw_k<<<dim3(8, 3), 256, 0, stream>>>(Wa, Wq, Wk, Wd2, ba, bd2, Waq, Wak, Wda, cbv);
  inproj_ln_k<<<BNT / 64, 256, 0, stream>>>(x, Win, bin, g1, b1, h, hnb);
  knn_k<<<BB * (NN / 4), 256, 0, stream>>>(p, idxw);
  gemm_qkv_k<<<dim3(BNT / 64, 6), 256, 0, stream>>>(hnb, Waq, Wak, Wv, qa, kab, vb);
  attn_k<<<BNT / 4, 256, 0, stream>>>(qa, kab, vb, p, idxw, Wd1, bd1, Wd2, Wda, cbv, bd2,
                                      g2, b2, h, hres, h2);
  gemm_k<1><<<dim3(BNT / 64, 8), 256, 0, stream>>>(h2, Wf1, bf1, nullptr, g, nullptr, 4 * CC, CC);
  gemm_k<2><<<dim3(BNT / 64, 2), 256, 0, stream>>>(g, Wf2, bf2, out, nullptr, hres, CC, 4 * CC);
}